// Round 1
// 198.396 us; speedup vs baseline: 1.0698x; 1.0698x over previous
//
#include <hip/hip_runtime.h>
#include <stdint.h>

#define CIN 256
#define FDIM 128
#define NSP 4096
#define EPS 1e-5f

typedef __attribute__((ext_vector_type(8))) short short8;
typedef __attribute__((ext_vector_type(4))) float f32x4;
typedef __attribute__((ext_vector_type(16))) float f32x16;

__device__ __forceinline__ short f2bf(float f) {
  union { float f; uint32_t u; } v; v.f = f;
  uint32_t r = v.u + 0x7fffu + ((v.u >> 16) & 1u);
  return (short)(r >> 16);
}
__device__ __forceinline__ float bf2f(short h) {
  union { uint32_t u; float f; } v; v.u = ((uint32_t)(uint16_t)h) << 16;
  return v.f;
}

// ---------------- prep: weights -> bf16 ----------------
__global__ void prep_weights(const float* __restrict__ Wg, const float* __restrict__ Wt,
                             const float* __restrict__ Wp, const float* __restrict__ Wz,
                             short* __restrict__ Wbf, short* __restrict__ Wzbf) {
  int idx = blockIdx.x * 256 + threadIdx.x;
  if (idx < 384 * 256) {
    int row = idx >> 8, col = idx & 255;
    float v;
    if (row < 128)       v = Wt[row * 256 + col];
    else if (row < 256)  v = Wp[(row - 128) * 256 + col];
    else                 v = Wg[(row - 256) * 256 + col];
    Wbf[idx] = f2bf(v);
  } else {
    int j = idx - 384 * 256;
    if (j < 256 * 128) Wzbf[j] = f2bf(Wz[j]);
  }
}

// ---------------- prep: x [B,C,N] fp32 -> xT [B,N,C] bf16 ----------------
__global__ void prep_xT(const float* __restrict__ x, short* __restrict__ xT) {
  __shared__ float tile[32][33];
  int b = blockIdx.z, c0 = blockIdx.y * 32, n0 = blockIdx.x * 32;
  int r = threadIdx.x >> 5, c = threadIdx.x & 31;
  const float* xb = x + (size_t)b * CIN * NSP;
#pragma unroll
  for (int k = 0; k < 4; k++)
    tile[r + 8 * k][c] = xb[(size_t)(c0 + r + 8 * k) * NSP + n0 + c];
  __syncthreads();
  short* xTb = xT + (size_t)b * NSP * CIN;
#pragma unroll
  for (int k = 0; k < 4; k++)
    xTb[(size_t)(n0 + r + 8 * k) * CIN + c0 + c] = f2bf(tile[c][r + 8 * k]);
}

// ---------------- projections: grid (512, 3) ----------------
// y=0: theta [B,N,F]; y=1: K(=phi^T) [B,N,F]; y=2: gT [B,F,N]
// block: 32 rows; wave: row-half (w&1), feature-quarter (w>>1)
__global__ void __launch_bounds__(256)
proj_kernel(const short* __restrict__ xT, const short* __restrict__ Wbf,
            const float* __restrict__ bt, const float* __restrict__ bp,
            const float* __restrict__ bg,
            short* __restrict__ theta, short* __restrict__ Kb, short* __restrict__ gT) {
  __shared__ short lds[5120];  // max(32*136, 128*40)
  int bx = blockIdx.x;
  int b = bx >> 7;
  int n0 = (bx & 127) << 5;
  int p = blockIdx.y;
  int t = threadIdx.x, w = t >> 6, lane = t & 63, l15 = lane & 15, quad = lane >> 4;

  const short* arow = xT + (size_t)(b * NSP + n0 + (w & 1) * 16 + l15) * CIN;
  short8 a[8];
#pragma unroll
  for (int s = 0; s < 8; s++) a[s] = *(const short8*)(arow + s * 32 + quad * 8);

  const short* Wsrc = Wbf + p * 128 * 256;
  f32x4 zero = {0.f, 0.f, 0.f, 0.f};
  f32x4 acc[4];
#pragma unroll
  for (int i = 0; i < 4; i++) acc[i] = zero;

#pragma unroll
  for (int s = 0; s < 8; s++) {
#pragma unroll
    for (int ft = 0; ft < 4; ft++) {
      int ftg = (w >> 1) * 4 + ft;
      short8 bfr = *(const short8*)(Wsrc + (ftg * 16 + l15) * 256 + s * 32 + quad * 8);
      acc[ft] = __builtin_amdgcn_mfma_f32_16x16x32_bf16(a[s], bfr, acc[ft], 0, 0, 0);
    }
  }

  const float* bias = (p == 0) ? bt : (p == 1) ? bp : bg;
  if (p < 2) {
#pragma unroll
    for (int ft = 0; ft < 4; ft++) {
      int ftg = (w >> 1) * 4 + ft;
      float bv = bias[ftg * 16 + l15];
#pragma unroll
      for (int rr = 0; rr < 4; rr++) {
        int n = (w & 1) * 16 + quad * 4 + rr;
        lds[n * 136 + ftg * 16 + l15] = f2bf(acc[ft][rr] + bv);
      }
    }
    __syncthreads();
    short* dst = ((p == 0) ? theta : Kb) + (size_t)(b * NSP + n0) * FDIM;
#pragma unroll
    for (int i = 0; i < 2; i++) {
      int flat = t + 256 * i;
      int row = flat >> 4, ch = flat & 15;
      *(short8*)(dst + (size_t)row * FDIM + ch * 8) = *(const short8*)(lds + row * 136 + ch * 8);
    }
  } else {
#pragma unroll
    for (int ft = 0; ft < 4; ft++) {
      int ftg = (w >> 1) * 4 + ft;
      float bv = bias[ftg * 16 + l15];
#pragma unroll
      for (int rr = 0; rr < 4; rr++) {
        int n = (w & 1) * 16 + quad * 4 + rr;
        lds[(ftg * 16 + l15) * 40 + n] = f2bf(acc[ft][rr] + bv);
      }
    }
    __syncthreads();
    short* dst = gT + (size_t)b * FDIM * NSP + n0;
#pragma unroll
    for (int i = 0; i < 2; i++) {
      int flat = t + 256 * i;
      int f = flat >> 2, c = flat & 3;
      *(short8*)(dst + (size_t)f * NSP + c * 8) = *(const short8*)(lds + f * 40 + c * 8);
    }
  }
}

// ---------------- flash attention v4: exclusive-q waves + dbuf LDS + reg prefetch ----
// Each wave owns 32 q-rows (w*32); all 4 waves share the 32-key tile -> no merge phase.
// S^T = K @ Q^T (A=K from LDS, B=Q in regs); C: col(lane&31)=q, row=key.
// LDS: 2 stage buffers of {K [32][136], V [128][40]}; ONE barrier per tile.
// T14: next tile's global loads issued into regs before compute, committed to the
// other LDS buffer after compute -> load latency hidden, no vmcnt crossing barriers.
__global__ void __launch_bounds__(256, 2)
flash_kernel(const short* __restrict__ thetab, const short* __restrict__ Kb,
             const short* __restrict__ gT, short* __restrict__ opart,
             float* __restrict__ lpart) {
  __shared__ __attribute__((aligned(16))) char smem[37888];
  // buf i at i*18944: K @+0 (8704 B), V @+8704 (10240 B)

  const int bx = blockIdx.x;
  const int b  = bx >> 7;
  const int r  = bx & 127;
  const int q0 = (r >> 2) << 7;
  const int kc = r & 3;
  const int t = threadIdx.x, w = t >> 6, lane = t & 63;
  const int l31 = lane & 31, h = lane >> 5;
  const int qw = q0 + w * 32;

  const short* Qsrc = thetab + (size_t)b * NSP * FDIM;
  const short* Ksrc = Kb + (size_t)b * NSP * FDIM;
  const short* Vsrc = gT + (size_t)b * FDIM * NSP;

  // Q B-frags for this wave's 32 q-rows
  short8 qf[8];
#pragma unroll
  for (int s = 0; s < 8; s++)
    qf[s] = *(const short8*)(Qsrc + (size_t)(qw + l31) * FDIM + s * 16 + h * 8);

  f32x16 O[4];
#pragma unroll
  for (int i = 0; i < 4; i++)
#pragma unroll
    for (int j = 0; j < 16; j++) O[i][j] = 0.f;
  float lsum = 0.f;

  // staging slots (constant per thread): 2 K short8 + 2 V short8 per thread
  const int kr0 = t >> 4, kcc0 = t & 15;
  const int kr1 = 16 + (t >> 4);
  const int vf0 = t >> 2, vcc0 = t & 3;
  const int vf1 = 64 + (t >> 2);

  const int kA0 = kc << 10;
  short8 rK0, rK1, rV0, rV1;

  // prologue: stage tile 0 into buf0
  {
    rK0 = *(const short8*)(Ksrc + (size_t)(kA0 + kr0) * FDIM + kcc0 * 8);
    rK1 = *(const short8*)(Ksrc + (size_t)(kA0 + kr1) * FDIM + kcc0 * 8);
    rV0 = *(const short8*)(Vsrc + (size_t)vf0 * NSP + kA0 + vcc0 * 8);
    rV1 = *(const short8*)(Vsrc + (size_t)vf1 * NSP + kA0 + vcc0 * 8);
    short* Kd = (short*)(smem);
    short* Vd = (short*)(smem + 8704);
    *(short8*)(Kd + kr0 * 136 + kcc0 * 8) = rK0;
    *(short8*)(Kd + kr1 * 136 + kcc0 * 8) = rK1;
    *(short8*)(Vd + vf0 * 40 + vcc0 * 8) = rV0;
    *(short8*)(Vd + vf1 * 40 + vcc0 * 8) = rV1;
  }

#pragma unroll 2
  for (int it = 0; it < 32; ++it) {
    __syncthreads();  // stage writes for tile `it` visible; reads of other buf done
    if (it < 31) {
      int kk = kA0 + (it + 1) * 32;
      rK0 = *(const short8*)(Ksrc + (size_t)(kk + kr0) * FDIM + kcc0 * 8);
      rK1 = *(const short8*)(Ksrc + (size_t)(kk + kr1) * FDIM + kcc0 * 8);
      rV0 = *(const short8*)(Vsrc + (size_t)vf0 * NSP + kk + vcc0 * 8);
      rV1 = *(const short8*)(Vsrc + (size_t)vf1 * NSP + kk + vcc0 * 8);
    }
    const short* Kl = (const short*)(smem + (it & 1) * 18944);
    const short* Vl = (const short*)(smem + (it & 1) * 18944 + 8704);

    // QK: S^T[key][q]
    f32x16 S;
#pragma unroll
    for (int j = 0; j < 16; j++) S[j] = 0.f;
    __builtin_amdgcn_s_setprio(1);
#pragma unroll
    for (int s = 0; s < 8; s++) {
      short8 ak = *(const short8*)(Kl + l31 * 136 + s * 16 + h * 8);
      S = __builtin_amdgcn_mfma_f32_32x32x16_bf16(ak, qf[s], S, 0, 0, 0);
    }
    __builtin_amdgcn_s_setprio(0);

    // exp (scores bounded, no overflow) + pairwise tree sum
    float p[16];
#pragma unroll
    for (int i = 0; i < 16; i++) p[i] = __expf(S[i]);
    float t8[8];
#pragma unroll
    for (int i = 0; i < 8; i++) t8[i] = p[2 * i] + p[2 * i + 1];
    lsum += ((t8[0] + t8[1]) + (t8[2] + t8[3])) + ((t8[4] + t8[5]) + (t8[6] + t8[7]));

    // lane^32 exchange -> PV A-frags (P[q=l31][key = tt*16 + h*8 + j])
    short8 Af[2];
#pragma unroll
    for (int tt = 0; tt < 2; tt++) {
      const int rb = tt * 8;
      short8 af;
#pragma unroll
      for (int rr = 0; rr < 4; rr++) {
        float qv = h ? p[rb + rr] : p[rb + 4 + rr];
        float wv = __shfl_xor(qv, 32, 64);
        float e0 = h ? wv : p[rb + rr];
        float e1 = h ? p[rb + 4 + rr] : wv;
        af[rr] = f2bf(e0);
        af[4 + rr] = f2bf(e1);
      }
      Af[tt] = af;
    }

    // PV: O[q][f] += P x V
    __builtin_amdgcn_s_setprio(1);
#pragma unroll
    for (int ft = 0; ft < 4; ft++) {
#pragma unroll
      for (int tt = 0; tt < 2; tt++) {
        short8 bv = *(const short8*)(Vl + (ft * 32 + l31) * 40 + tt * 16 + h * 8);
        O[ft] = __builtin_amdgcn_mfma_f32_32x32x16_bf16(Af[tt], bv, O[ft], 0, 0, 0);
      }
    }
    __builtin_amdgcn_s_setprio(0);

    // commit next tile to the other buffer (no barrier needed: disjoint buffer)
    if (it < 31) {
      short* Kd = (short*)(smem + ((it + 1) & 1) * 18944);
      short* Vd = (short*)(smem + ((it + 1) & 1) * 18944 + 8704);
      *(short8*)(Kd + kr0 * 136 + kcc0 * 8) = rK0;
      *(short8*)(Kd + kr1 * 136 + kcc0 * 8) = rK1;
      *(short8*)(Vd + vf0 * 40 + vcc0 * 8) = rV0;
      *(short8*)(Vd + vf1 * 40 + vcc0 * 8) = rV1;
    }
  }

  lsum += __shfl_xor(lsum, 32, 64);

  __syncthreads();  // all compute reads done before overwriting smem with transposes
  // per-wave transpose slice [32][136] -> coalesced short8 stores
  short* tr = (short*)smem + w * 32 * 136;
#pragma unroll
  for (int ft = 0; ft < 4; ft++) {
#pragma unroll
    for (int reg = 0; reg < 16; reg++) {
      int rowq = (reg & 3) + 8 * (reg >> 2) + 4 * h;
      tr[rowq * 136 + ft * 32 + l31] = f2bf(O[ft][reg]);
    }
  }
  short* od = opart + ((size_t)(kc * 4 + b) * NSP + qw) * FDIM;
#pragma unroll
  for (int i = 0; i < 8; i++) {
    int slot = lane + 64 * i;
    int row = slot >> 4, c = slot & 15;
    *(short8*)(od + (size_t)row * FDIM + c * 8) = *(const short8*)(tr + row * 136 + c * 8);
  }
  if (h == 0) lpart[(size_t)(kc * 4 + b) * NSP + qw + l31] = lsum;
}

// ---------------- z projection + fused split-K combine + LN partial sums ----------------
// grid (512, 2): block 32 rows x 128 out-ch; wave: row-half (w&1), ch-quarter (w>>1)
__global__ void __launch_bounds__(256)
zproj_kernel(const short* __restrict__ opart, const float* __restrict__ lpart,
             const short* __restrict__ Wzbf, const float* __restrict__ bz,
             short* __restrict__ zb, float* __restrict__ psums) {
  __shared__ short ldsT[128 * 40];
  __shared__ float wsum[4][2];
  int bx = blockIdx.x;
  int b = bx >> 7;
  int n0 = (bx & 127) << 5;
  int ch0 = blockIdx.y * 128;
  int t = threadIdx.x, w = t >> 6, lane = t & 63, l15 = lane & 15, quad = lane >> 4;

  int row = n0 + (w & 1) * 16 + l15;
  float L = 0.f;
#pragma unroll
  for (int kcc = 0; kcc < 4; kcc++) L += lpart[(size_t)(kcc * 4 + b) * NSP + row];
  float inv = 1.0f / L;

  short8 a[4];
#pragma unroll
  for (int s = 0; s < 4; s++) {
    float accv[8] = {0, 0, 0, 0, 0, 0, 0, 0};
#pragma unroll
    for (int kcc = 0; kcc < 4; kcc++) {
      short8 v = *(const short8*)(opart + ((size_t)(kcc * 4 + b) * NSP + row) * FDIM + s * 32 + quad * 8);
#pragma unroll
      for (int j = 0; j < 8; j++) accv[j] += bf2f(v[j]);
    }
    short8 av;
#pragma unroll
    for (int j = 0; j < 8; j++) av[j] = f2bf(accv[j] * inv);
    a[s] = av;
  }

  f32x4 zero = {0.f, 0.f, 0.f, 0.f};
  f32x4 acc[4];
#pragma unroll
  for (int i = 0; i < 4; i++) acc[i] = zero;
#pragma unroll
  for (int s = 0; s < 4; s++) {
#pragma unroll
    for (int ct = 0; ct < 4; ct++) {
      int co = ch0 + (w >> 1) * 64 + ct * 16 + l15;
      short8 bfr = *(const short8*)(Wzbf + (size_t)co * FDIM + s * 32 + quad * 8);
      acc[ct] = __builtin_amdgcn_mfma_f32_16x16x32_bf16(a[s], bfr, acc[ct], 0, 0, 0);
    }
  }

  float s1 = 0.0f, s2 = 0.0f;
#pragma unroll
  for (int ct = 0; ct < 4; ct++) {
    int cg = (w >> 1) * 64 + ct * 16 + l15;
    float bv = bz[ch0 + cg];
#pragma unroll
    for (int rr = 0; rr < 4; rr++) {
      float v = acc[ct][rr] + bv;
      s1 += v; s2 += v * v;
      ldsT[cg * 40 + (w & 1) * 16 + quad * 4 + rr] = f2bf(v);
    }
  }
#pragma unroll
  for (int off = 32; off >= 1; off >>= 1) {
    s1 += __shfl_xor(s1, off, 64);
    s2 += __shfl_xor(s2, off, 64);
  }
  if (lane == 0) { wsum[w][0] = s1; wsum[w][1] = s2; }
  __syncthreads();
  if (t == 0) {
    int bid = blockIdx.y * 512 + bx;
    psums[bid * 2] = wsum[0][0] + wsum[1][0] + wsum[2][0] + wsum[3][0];
    psums[bid * 2 + 1] = wsum[0][1] + wsum[1][1] + wsum[2][1] + wsum[3][1];
  }
  short* dst = zb + (size_t)b * CIN * NSP + (size_t)ch0 * NSP + n0;
#pragma unroll
  for (int i = 0; i < 2; i++) {
    int flat = t + 256 * i;
    int c = flat >> 2, ch = flat & 3;
    *(short8*)(dst + (size_t)c * NSP + ch * 8) = *(const short8*)(ldsT + c * 40 + ch * 8);
  }
}

// ---------------- reduce per-block LN partials -> per-sample sums ----------------
__global__ void reduce_sums(const float* __restrict__ psums, float* __restrict__ sums) {
  __shared__ float red[8];
  int t = threadIdx.x;
  if (t < 8) red[t] = 0.f;
  __syncthreads();
  for (int i = t; i < 1024; i += 256) {
    int b = (i & 511) >> 7;
    atomicAdd(&red[b * 2], psums[i * 2]);
    atomicAdd(&red[b * 2 + 1], psums[i * 2 + 1]);
  }
  __syncthreads();
  if (t < 8) sums[t] = red[t];
}

// ---------------- LayerNorm + affine + residual ----------------
__global__ void __launch_bounds__(256)
finalize_kernel(const short* __restrict__ zbuf, const float* __restrict__ x,
                const float* __restrict__ lnw, const float* __restrict__ lnb,
                const float* __restrict__ sums, float* __restrict__ out) {
  int gid = blockIdx.x * 256 + threadIdx.x;
  size_t e0 = (size_t)gid * 8;
  int b = (int)(e0 >> 20);  // CIN*NSP = 2^20
  size_t ib = e0 & ((size_t)(1u << 20) - 1);
  float mean = sums[b * 2] * (1.0f / 1048576.0f);
  float var = sums[b * 2 + 1] * (1.0f / 1048576.0f) - mean * mean;
  float rs = rsqrtf(var + EPS);
  short8 zv = *(const short8*)(zbuf + e0);
#pragma unroll
  for (int k = 0; k < 8; k++) {
    float z = bf2f(zv[k]);
    out[e0 + k] = (z - mean) * rs * lnw[ib + k] + lnb[ib + k] + x[e0 + k];
  }
}

extern "C" void kernel_launch(void* const* d_in, const int* in_sizes, int n_in,
                              void* d_out, int out_size, void* d_ws, size_t ws_size,
                              hipStream_t stream) {
  const float* x   = (const float*)d_in[0];
  const float* Wg  = (const float*)d_in[1];
  const float* bg  = (const float*)d_in[2];
  const float* Wt  = (const float*)d_in[3];
  const float* bt  = (const float*)d_in[4];
  const float* Wp  = (const float*)d_in[5];
  const float* bp  = (const float*)d_in[6];
  const float* Wz  = (const float*)d_in[7];
  const float* bz  = (const float*)d_in[8];
  const float* lnw = (const float*)d_in[9];
  const float* lnb = (const float*)d_in[10];
  float* out = (float*)d_out;

  // Workspace (~29.9 MB, lifetime overlaps):
  //  [0, 196608)           Wbf
  //  [196608, 262144)      Wzbf
  //  [262144, 17039360)    opart 16 MB; xT (8 MB) overlays its front (dead before flash)
  //  [17039360, 17301504)  lpart 256 KB
  //  [17301504, 21495808)  thetab 4 MB \__ zb (8 MB) overlays after flash
  //  [21495808, 25690112)  Kb 4 MB     /
  //  [25690112, 29884416)  gT 4 MB
  //  [29884416, +32)       sums; [29884448, +8192) psums
  char* ws = (char*)d_ws;
  short* Wbf    = (short*)(ws);
  short* Wzbf   = (short*)(ws + 196608);
  short* xT     = (short*)(ws + 262144);
  short* opart  = (short*)(ws + 262144);
  float* lpart  = (float*)(ws + 17039360);
  short* thetab = (short*)(ws + 17301504);
  short* Kb     = (short*)(ws + 21495808);
  short* gT     = (short*)(ws + 25690112);
  short* zb     = (short*)(ws + 17301504);
  float* sums   = (float*)(ws + 29884416);
  float* psums  = (float*)(ws + 29884448);

  prep_weights<<<512, 256, 0, stream>>>(Wg, Wt, Wp, Wz, Wbf, Wzbf);
  prep_xT<<<dim3(128, 8, 4), 256, 0, stream>>>(x, xT);
  proj_kernel<<<dim3(512, 3), 256, 0, stream>>>(xT, Wbf, bt, bp, bg, thetab, Kb, gT);
  flash_kernel<<<512, 256, 0, stream>>>(thetab, Kb, gT, opart, lpart);
  zproj_kernel<<<dim3(512, 2), 256, 0, stream>>>(opart, lpart, Wzbf, bz, zb, psums);
  reduce_sums<<<1, 256, 0, stream>>>(psums, sums);
  finalize_kernel<<<2048, 256, 0, stream>>>(zb, x, lnw, lnb, sums, out);
}

// Round 2
// 193.428 us; speedup vs baseline: 1.0973x; 1.0257x over previous
//
#include <hip/hip_runtime.h>
#include <stdint.h>

#define CIN 256
#define FDIM 128
#define NSP 4096
#define EPS 1e-5f

typedef __attribute__((ext_vector_type(8))) short short8;
typedef __attribute__((ext_vector_type(4))) float f32x4;
typedef __attribute__((ext_vector_type(16))) float f32x16;

__device__ __forceinline__ short f2bf(float f) {
  union { float f; uint32_t u; } v; v.f = f;
  uint32_t r = v.u + 0x7fffu + ((v.u >> 16) & 1u);
  return (short)(r >> 16);
}
__device__ __forceinline__ float bf2f(short h) {
  union { uint32_t u; float f; } v; v.u = ((uint32_t)(uint16_t)h) << 16;
  return v.f;
}

// ---------------- prep: weights -> bf16 ----------------
__global__ void prep_weights(const float* __restrict__ Wg, const float* __restrict__ Wt,
                             const float* __restrict__ Wp, const float* __restrict__ Wz,
                             short* __restrict__ Wbf, short* __restrict__ Wzbf) {
  int idx = blockIdx.x * 256 + threadIdx.x;
  if (idx < 384 * 256) {
    int row = idx >> 8, col = idx & 255;
    float v;
    if (row < 128)       v = Wt[row * 256 + col];
    else if (row < 256)  v = Wp[(row - 128) * 256 + col];
    else                 v = Wg[(row - 256) * 256 + col];
    Wbf[idx] = f2bf(v);
  } else {
    int j = idx - 384 * 256;
    if (j < 256 * 128) Wzbf[j] = f2bf(Wz[j]);
  }
}

// ---------------- prep: x [B,C,N] fp32 -> xT [B,N,C] bf16 ----------------
__global__ void prep_xT(const float* __restrict__ x, short* __restrict__ xT) {
  __shared__ float tile[32][33];
  int b = blockIdx.z, c0 = blockIdx.y * 32, n0 = blockIdx.x * 32;
  int r = threadIdx.x >> 5, c = threadIdx.x & 31;
  const float* xb = x + (size_t)b * CIN * NSP;
#pragma unroll
  for (int k = 0; k < 4; k++)
    tile[r + 8 * k][c] = xb[(size_t)(c0 + r + 8 * k) * NSP + n0 + c];
  __syncthreads();
  short* xTb = xT + (size_t)b * NSP * CIN;
#pragma unroll
  for (int k = 0; k < 4; k++)
    xTb[(size_t)(n0 + r + 8 * k) * CIN + c0 + c] = f2bf(tile[c][r + 8 * k]);
}

// ---------------- projections: grid (512, 3) ----------------
__global__ void __launch_bounds__(256)
proj_kernel(const short* __restrict__ xT, const short* __restrict__ Wbf,
            const float* __restrict__ bt, const float* __restrict__ bp,
            const float* __restrict__ bg,
            short* __restrict__ theta, short* __restrict__ Kb, short* __restrict__ gT) {
  __shared__ short lds[5120];  // max(32*136, 128*40)
  int bx = blockIdx.x;
  int b = bx >> 7;
  int n0 = (bx & 127) << 5;
  int p = blockIdx.y;
  int t = threadIdx.x, w = t >> 6, lane = t & 63, l15 = lane & 15, quad = lane >> 4;

  const short* arow = xT + (size_t)(b * NSP + n0 + (w & 1) * 16 + l15) * CIN;
  short8 a[8];
#pragma unroll
  for (int s = 0; s < 8; s++) a[s] = *(const short8*)(arow + s * 32 + quad * 8);

  const short* Wsrc = Wbf + p * 128 * 256;
  f32x4 zero = {0.f, 0.f, 0.f, 0.f};
  f32x4 acc[4];
#pragma unroll
  for (int i = 0; i < 4; i++) acc[i] = zero;

#pragma unroll
  for (int s = 0; s < 8; s++) {
#pragma unroll
    for (int ft = 0; ft < 4; ft++) {
      int ftg = (w >> 1) * 4 + ft;
      short8 bfr = *(const short8*)(Wsrc + (ftg * 16 + l15) * 256 + s * 32 + quad * 8);
      acc[ft] = __builtin_amdgcn_mfma_f32_16x16x32_bf16(a[s], bfr, acc[ft], 0, 0, 0);
    }
  }

  const float* bias = (p == 0) ? bt : (p == 1) ? bp : bg;
  if (p < 2) {
#pragma unroll
    for (int ft = 0; ft < 4; ft++) {
      int ftg = (w >> 1) * 4 + ft;
      float bv = bias[ftg * 16 + l15];
#pragma unroll
      for (int rr = 0; rr < 4; rr++) {
        int n = (w & 1) * 16 + quad * 4 + rr;
        lds[n * 136 + ftg * 16 + l15] = f2bf(acc[ft][rr] + bv);
      }
    }
    __syncthreads();
    short* dst = ((p == 0) ? theta : Kb) + (size_t)(b * NSP + n0) * FDIM;
#pragma unroll
    for (int i = 0; i < 2; i++) {
      int flat = t + 256 * i;
      int row = flat >> 4, ch = flat & 15;
      *(short8*)(dst + (size_t)row * FDIM + ch * 8) = *(const short8*)(lds + row * 136 + ch * 8);
    }
  } else {
#pragma unroll
    for (int ft = 0; ft < 4; ft++) {
      int ftg = (w >> 1) * 4 + ft;
      float bv = bias[ftg * 16 + l15];
#pragma unroll
      for (int rr = 0; rr < 4; rr++) {
        int n = (w & 1) * 16 + quad * 4 + rr;
        lds[(ftg * 16 + l15) * 40 + n] = f2bf(acc[ft][rr] + bv);
      }
    }
    __syncthreads();
    short* dst = gT + (size_t)b * FDIM * NSP + n0;
#pragma unroll
    for (int i = 0; i < 2; i++) {
      int flat = t + 256 * i;
      int f = flat >> 2, c = flat & 3;
      *(short8*)(dst + (size_t)f * NSP + c * 8) = *(const short8*)(lds + f * 40 + c * 8);
    }
  }
}

// ---------------- flash attention v5: KVBLK=64 dbuf + cvt_pk/permlane P-exchange ----
// Each wave owns 32 q-rows; all 4 waves share the 64-key tile (two 32-key subtiles
// in the proven [32][136]/[128][40] layouts). 16 iterations, ONE barrier each.
// S^T = K @ Q^T; C: col(lane&31)=q, row=key. P->A-frag via v_cvt_pk_bf16_f32 +
// v_permlane32_swap_b32 (T12): swap(W0,W2)->(word0,word2), swap(W1,W3)->(word1,word3).
__global__ void __launch_bounds__(256, 2)
flash_kernel(const short* __restrict__ thetab, const short* __restrict__ Kb,
             const short* __restrict__ gT, short* __restrict__ opart,
             float* __restrict__ lpart) {
  __shared__ __attribute__((aligned(16))) char smem[75776];
  // buf i at i*37888: Ka @+0 (8704), Kb @+8704, Va @+17408 (10240), Vb @+27648

  const int bx = blockIdx.x;
  const int b  = bx >> 7;
  const int r  = bx & 127;
  const int q0 = (r >> 2) << 7;
  const int kc = r & 3;
  const int t = threadIdx.x, w = t >> 6, lane = t & 63;
  const int l31 = lane & 31, h = lane >> 5;
  const int qw = q0 + w * 32;

  const short* Qsrc = thetab + (size_t)b * NSP * FDIM;
  const short* Ksrc = Kb + (size_t)b * NSP * FDIM;
  const short* Vsrc = gT + (size_t)b * FDIM * NSP;

  // Q B-frags for this wave's 32 q-rows
  short8 qf[8];
#pragma unroll
  for (int s = 0; s < 8; s++)
    qf[s] = *(const short8*)(Qsrc + (size_t)(qw + l31) * FDIM + s * 16 + h * 8);

  f32x16 O[4];
#pragma unroll
  for (int i = 0; i < 4; i++)
#pragma unroll
    for (int j = 0; j < 16; j++) O[i][j] = 0.f;
  float lsum = 0.f;

  // staging slots (constant per thread)
  const int kr0 = t >> 4, kcc0 = t & 15;
  const int kr1 = 16 + (t >> 4);
  const int vf0 = t >> 2, vcc0 = t & 3;
  const int vf1 = 64 + (t >> 2);

  const int kA0 = kc << 10;
  short8 rKa0, rKa1, rKb0, rKb1, rVa0, rVa1, rVb0, rVb1;

  // prologue: stage tile 0 (keys kA0..kA0+63) into buf0
  {
    rKa0 = *(const short8*)(Ksrc + (size_t)(kA0 + kr0) * FDIM + kcc0 * 8);
    rKa1 = *(const short8*)(Ksrc + (size_t)(kA0 + kr1) * FDIM + kcc0 * 8);
    rKb0 = *(const short8*)(Ksrc + (size_t)(kA0 + 32 + kr0) * FDIM + kcc0 * 8);
    rKb1 = *(const short8*)(Ksrc + (size_t)(kA0 + 32 + kr1) * FDIM + kcc0 * 8);
    rVa0 = *(const short8*)(Vsrc + (size_t)vf0 * NSP + kA0 + vcc0 * 8);
    rVa1 = *(const short8*)(Vsrc + (size_t)vf1 * NSP + kA0 + vcc0 * 8);
    rVb0 = *(const short8*)(Vsrc + (size_t)vf0 * NSP + kA0 + 32 + vcc0 * 8);
    rVb1 = *(const short8*)(Vsrc + (size_t)vf1 * NSP + kA0 + 32 + vcc0 * 8);
    short* Ka = (short*)(smem);
    short* Kbd = (short*)(smem + 8704);
    short* Va = (short*)(smem + 17408);
    short* Vb = (short*)(smem + 27648);
    *(short8*)(Ka + kr0 * 136 + kcc0 * 8) = rKa0;
    *(short8*)(Ka + kr1 * 136 + kcc0 * 8) = rKa1;
    *(short8*)(Kbd + kr0 * 136 + kcc0 * 8) = rKb0;
    *(short8*)(Kbd + kr1 * 136 + kcc0 * 8) = rKb1;
    *(short8*)(Va + vf0 * 40 + vcc0 * 8) = rVa0;
    *(short8*)(Va + vf1 * 40 + vcc0 * 8) = rVa1;
    *(short8*)(Vb + vf0 * 40 + vcc0 * 8) = rVb0;
    *(short8*)(Vb + vf1 * 40 + vcc0 * 8) = rVb1;
  }

#pragma unroll 2
  for (int it = 0; it < 16; ++it) {
    __syncthreads();  // stage writes for tile `it` visible; reads of other buf done
    if (it < 15) {
      int kk = kA0 + (it + 1) * 64;
      rKa0 = *(const short8*)(Ksrc + (size_t)(kk + kr0) * FDIM + kcc0 * 8);
      rKa1 = *(const short8*)(Ksrc + (size_t)(kk + kr1) * FDIM + kcc0 * 8);
      rKb0 = *(const short8*)(Ksrc + (size_t)(kk + 32 + kr0) * FDIM + kcc0 * 8);
      rKb1 = *(const short8*)(Ksrc + (size_t)(kk + 32 + kr1) * FDIM + kcc0 * 8);
      rVa0 = *(const short8*)(Vsrc + (size_t)vf0 * NSP + kk + vcc0 * 8);
      rVa1 = *(const short8*)(Vsrc + (size_t)vf1 * NSP + kk + vcc0 * 8);
      rVb0 = *(const short8*)(Vsrc + (size_t)vf0 * NSP + kk + 32 + vcc0 * 8);
      rVb1 = *(const short8*)(Vsrc + (size_t)vf1 * NSP + kk + 32 + vcc0 * 8);
    }
    const char* bufc = smem + (it & 1) * 37888;
    const short* Kla = (const short*)(bufc);
    const short* Klb = (const short*)(bufc + 8704);
    const short* Vla = (const short*)(bufc + 17408);
    const short* Vlb = (const short*)(bufc + 27648);

    // QK: two independent accumulator chains (subtile A/B) interleaved
    f32x16 S0, S1;
#pragma unroll
    for (int j = 0; j < 16; j++) { S0[j] = 0.f; S1[j] = 0.f; }
    __builtin_amdgcn_s_setprio(1);
#pragma unroll
    for (int s = 0; s < 8; s++) {
      short8 ak0 = *(const short8*)(Kla + l31 * 136 + s * 16 + h * 8);
      short8 ak1 = *(const short8*)(Klb + l31 * 136 + s * 16 + h * 8);
      S0 = __builtin_amdgcn_mfma_f32_32x32x16_bf16(ak0, qf[s], S0, 0, 0, 0);
      S1 = __builtin_amdgcn_mfma_f32_32x32x16_bf16(ak1, qf[s], S1, 0, 0, 0);
    }
    __builtin_amdgcn_s_setprio(0);

    // softmax numerators + T12 pack/exchange -> PV A-frags
    short8 AfA[2], AfB[2];
#pragma unroll
    for (int sub = 0; sub < 2; sub++) {
      float p[16];
#pragma unroll
      for (int i = 0; i < 16; i++) p[i] = __expf(sub ? S1[i] : S0[i]);
      float t8[8];
#pragma unroll
      for (int i = 0; i < 8; i++) t8[i] = p[2 * i] + p[2 * i + 1];
      lsum += ((t8[0] + t8[1]) + (t8[2] + t8[3])) + ((t8[4] + t8[5]) + (t8[6] + t8[7]));

      uint32_t W[8];
#pragma unroll
      for (int j = 0; j < 8; j++)
        asm("v_cvt_pk_bf16_f32 %0, %1, %2" : "=v"(W[j]) : "v"(p[2 * j]), "v"(p[2 * j + 1]));
      // swap(d,s): d.hi <-> s.lo ; yields Af words uniformly for both lane halves
      asm("v_permlane32_swap_b32 %0, %1" : "+v"(W[0]), "+v"(W[2]));
      asm("v_permlane32_swap_b32 %0, %1" : "+v"(W[1]), "+v"(W[3]));
      asm("v_permlane32_swap_b32 %0, %1" : "+v"(W[4]), "+v"(W[6]));
      asm("v_permlane32_swap_b32 %0, %1" : "+v"(W[5]), "+v"(W[7]));
      union { short8 s; uint32_t u[4]; } u0, u1;
      u0.u[0] = W[0]; u0.u[1] = W[1]; u0.u[2] = W[2]; u0.u[3] = W[3];
      u1.u[0] = W[4]; u1.u[1] = W[5]; u1.u[2] = W[6]; u1.u[3] = W[7];
      if (sub) { AfB[0] = u0.s; AfB[1] = u1.s; }
      else     { AfA[0] = u0.s; AfA[1] = u1.s; }
    }

    // PV: O[q][f] += P x V  (4 independent chains of depth 4)
    __builtin_amdgcn_s_setprio(1);
#pragma unroll
    for (int ft = 0; ft < 4; ft++) {
#pragma unroll
      for (int tt = 0; tt < 2; tt++) {
        short8 bva = *(const short8*)(Vla + (ft * 32 + l31) * 40 + tt * 16 + h * 8);
        O[ft] = __builtin_amdgcn_mfma_f32_32x32x16_bf16(AfA[tt], bva, O[ft], 0, 0, 0);
        short8 bvb = *(const short8*)(Vlb + (ft * 32 + l31) * 40 + tt * 16 + h * 8);
        O[ft] = __builtin_amdgcn_mfma_f32_32x32x16_bf16(AfB[tt], bvb, O[ft], 0, 0, 0);
      }
    }
    __builtin_amdgcn_s_setprio(0);

    // commit next tile to the other buffer (no barrier needed: disjoint buffer)
    if (it < 15) {
      char* nb = smem + ((it + 1) & 1) * 37888;
      short* Ka = (short*)(nb);
      short* Kbd = (short*)(nb + 8704);
      short* Va = (short*)(nb + 17408);
      short* Vb = (short*)(nb + 27648);
      *(short8*)(Ka + kr0 * 136 + kcc0 * 8) = rKa0;
      *(short8*)(Ka + kr1 * 136 + kcc0 * 8) = rKa1;
      *(short8*)(Kbd + kr0 * 136 + kcc0 * 8) = rKb0;
      *(short8*)(Kbd + kr1 * 136 + kcc0 * 8) = rKb1;
      *(short8*)(Va + vf0 * 40 + vcc0 * 8) = rVa0;
      *(short8*)(Va + vf1 * 40 + vcc0 * 8) = rVa1;
      *(short8*)(Vb + vf0 * 40 + vcc0 * 8) = rVb0;
      *(short8*)(Vb + vf1 * 40 + vcc0 * 8) = rVb1;
    }
  }

  lsum += __shfl_xor(lsum, 32, 64);

  __syncthreads();  // all compute reads done before overwriting smem with transposes
  // per-wave transpose slice [32][136] -> coalesced short8 stores
  short* tr = (short*)smem + w * 32 * 136;
#pragma unroll
  for (int ft = 0; ft < 4; ft++) {
#pragma unroll
    for (int reg = 0; reg < 16; reg++) {
      int rowq = (reg & 3) + 8 * (reg >> 2) + 4 * h;
      tr[rowq * 136 + ft * 32 + l31] = f2bf(O[ft][reg]);
    }
  }
  short* od = opart + ((size_t)(kc * 4 + b) * NSP + qw) * FDIM;
#pragma unroll
  for (int i = 0; i < 8; i++) {
    int slot = lane + 64 * i;
    int row = slot >> 4, c = slot & 15;
    *(short8*)(od + (size_t)row * FDIM + c * 8) = *(const short8*)(tr + row * 136 + c * 8);
  }
  if (h == 0) lpart[(size_t)(kc * 4 + b) * NSP + qw + l31] = lsum;
}

// ---------------- z projection + fused split-K combine + LN partial sums ----------------
__global__ void __launch_bounds__(256)
zproj_kernel(const short* __restrict__ opart, const float* __restrict__ lpart,
             const short* __restrict__ Wzbf, const float* __restrict__ bz,
             short* __restrict__ zb, float* __restrict__ psums) {
  __shared__ short ldsT[128 * 40];
  __shared__ float wsum[4][2];
  int bx = blockIdx.x;
  int b = bx >> 7;
  int n0 = (bx & 127) << 5;
  int ch0 = blockIdx.y * 128;
  int t = threadIdx.x, w = t >> 6, lane = t & 63, l15 = lane & 15, quad = lane >> 4;

  int row = n0 + (w & 1) * 16 + l15;
  float L = 0.f;
#pragma unroll
  for (int kcc = 0; kcc < 4; kcc++) L += lpart[(size_t)(kcc * 4 + b) * NSP + row];
  float inv = 1.0f / L;

  short8 a[4];
#pragma unroll
  for (int s = 0; s < 4; s++) {
    float accv[8] = {0, 0, 0, 0, 0, 0, 0, 0};
#pragma unroll
    for (int kcc = 0; kcc < 4; kcc++) {
      short8 v = *(const short8*)(opart + ((size_t)(kcc * 4 + b) * NSP + row) * FDIM + s * 32 + quad * 8);
#pragma unroll
      for (int j = 0; j < 8; j++) accv[j] += bf2f(v[j]);
    }
    short8 av;
#pragma unroll
    for (int j = 0; j < 8; j++) av[j] = f2bf(accv[j] * inv);
    a[s] = av;
  }

  f32x4 zero = {0.f, 0.f, 0.f, 0.f};
  f32x4 acc[4];
#pragma unroll
  for (int i = 0; i < 4; i++) acc[i] = zero;
#pragma unroll
  for (int s = 0; s < 4; s++) {
#pragma unroll
    for (int ct = 0; ct < 4; ct++) {
      int co = ch0 + (w >> 1) * 64 + ct * 16 + l15;
      short8 bfr = *(const short8*)(Wzbf + (size_t)co * FDIM + s * 32 + quad * 8);
      acc[ct] = __builtin_amdgcn_mfma_f32_16x16x32_bf16(a[s], bfr, acc[ct], 0, 0, 0);
    }
  }

  float s1 = 0.0f, s2 = 0.0f;
#pragma unroll
  for (int ct = 0; ct < 4; ct++) {
    int cg = (w >> 1) * 64 + ct * 16 + l15;
    float bv = bz[ch0 + cg];
#pragma unroll
    for (int rr = 0; rr < 4; rr++) {
      float v = acc[ct][rr] + bv;
      s1 += v; s2 += v * v;
      ldsT[cg * 40 + (w & 1) * 16 + quad * 4 + rr] = f2bf(v);
    }
  }
#pragma unroll
  for (int off = 32; off >= 1; off >>= 1) {
    s1 += __shfl_xor(s1, off, 64);
    s2 += __shfl_xor(s2, off, 64);
  }
  if (lane == 0) { wsum[w][0] = s1; wsum[w][1] = s2; }
  __syncthreads();
  if (t == 0) {
    int bid = blockIdx.y * 512 + bx;
    psums[bid * 2] = wsum[0][0] + wsum[1][0] + wsum[2][0] + wsum[3][0];
    psums[bid * 2 + 1] = wsum[0][1] + wsum[1][1] + wsum[2][1] + wsum[3][1];
  }
  short* dst = zb + (size_t)b * CIN * NSP + (size_t)ch0 * NSP + n0;
#pragma unroll
  for (int i = 0; i < 2; i++) {
    int flat = t + 256 * i;
    int c = flat >> 2, ch = flat & 3;
    *(short8*)(dst + (size_t)c * NSP + ch * 8) = *(const short8*)(ldsT + c * 40 + ch * 8);
  }
}

// ---------------- reduce per-block LN partials -> per-sample sums ----------------
__global__ void reduce_sums(const float* __restrict__ psums, float* __restrict__ sums) {
  __shared__ float red[8];
  int t = threadIdx.x;
  if (t < 8) red[t] = 0.f;
  __syncthreads();
  for (int i = t; i < 1024; i += 256) {
    int b = (i & 511) >> 7;
    atomicAdd(&red[b * 2], psums[i * 2]);
    atomicAdd(&red[b * 2 + 1], psums[i * 2 + 1]);
  }
  __syncthreads();
  if (t < 8) sums[t] = red[t];
}

// ---------------- LayerNorm + affine + residual ----------------
__global__ void __launch_bounds__(256)
finalize_kernel(const short* __restrict__ zbuf, const float* __restrict__ x,
                const float* __restrict__ lnw, const float* __restrict__ lnb,
                const float* __restrict__ sums, float* __restrict__ out) {
  int gid = blockIdx.x * 256 + threadIdx.x;
  size_t e0 = (size_t)gid * 8;
  int b = (int)(e0 >> 20);  // CIN*NSP = 2^20
  size_t ib = e0 & ((size_t)(1u << 20) - 1);
  float mean = sums[b * 2] * (1.0f / 1048576.0f);
  float var = sums[b * 2 + 1] * (1.0f / 1048576.0f) - mean * mean;
  float rs = rsqrtf(var + EPS);
  short8 zv = *(const short8*)(zbuf + e0);
#pragma unroll
  for (int k = 0; k < 8; k++) {
    float z = bf2f(zv[k]);
    out[e0 + k] = (z - mean) * rs * lnw[ib + k] + lnb[ib + k] + x[e0 + k];
  }
}

extern "C" void kernel_launch(void* const* d_in, const int* in_sizes, int n_in,
                              void* d_out, int out_size, void* d_ws, size_t ws_size,
                              hipStream_t stream) {
  const float* x   = (const float*)d_in[0];
  const float* Wg  = (const float*)d_in[1];
  const float* bg  = (const float*)d_in[2];
  const float* Wt  = (const float*)d_in[3];
  const float* bt  = (const float*)d_in[4];
  const float* Wp  = (const float*)d_in[5];
  const float* bp  = (const float*)d_in[6];
  const float* Wz  = (const float*)d_in[7];
  const float* bz  = (const float*)d_in[8];
  const float* lnw = (const float*)d_in[9];
  const float* lnb = (const float*)d_in[10];
  float* out = (float*)d_out;

  // Workspace (~29.9 MB, lifetime overlaps):
  //  [0, 196608)           Wbf
  //  [196608, 262144)      Wzbf
  //  [262144, 17039360)    opart 16 MB; xT (8 MB) overlays its front (dead before flash)
  //  [17039360, 17301504)  lpart 256 KB
  //  [17301504, 21495808)  thetab 4 MB \__ zb (8 MB) overlays after flash
  //  [21495808, 25690112)  Kb 4 MB     /
  //  [25690112, 29884416)  gT 4 MB
  //  [29884416, +32)       sums; [29884448, +8192) psums
  char* ws = (char*)d_ws;
  short* Wbf    = (short*)(ws);
  short* Wzbf   = (short*)(ws + 196608);
  short* xT     = (short*)(ws + 262144);
  short* opart  = (short*)(ws + 262144);
  float* lpart  = (float*)(ws + 17039360);
  short* thetab = (short*)(ws + 17301504);
  short* Kb     = (short*)(ws + 21495808);
  short* gT     = (short*)(ws + 25690112);
  short* zb     = (short*)(ws + 17301504);
  float* sums   = (float*)(ws + 29884416);
  float* psums  = (float*)(ws + 29884448);

  prep_weights<<<512, 256, 0, stream>>>(Wg, Wt, Wp, Wz, Wbf, Wzbf);
  prep_xT<<<dim3(128, 8, 4), 256, 0, stream>>>(x, xT);
  proj_kernel<<<dim3(512, 3), 256, 0, stream>>>(xT, Wbf, bt, bp, bg, thetab, Kb, gT);
  flash_kernel<<<512, 256, 0, stream>>>(thetab, Kb, gT, opart, lpart);
  zproj_kernel<<<dim3(512, 2), 256, 0, stream>>>(opart, lpart, Wzbf, bz, zb, psums);
  reduce_sums<<<1, 256, 0, stream>>>(psums, sums);
  finalize_kernel<<<2048, 256, 0, stream>>>(zb, x, lnw, lnb, sums, out);
}